// Round 5
// baseline (461.625 us; speedup 1.0000x reference)
//
#include <hip/hip_runtime.h>
#include <hip/hip_bf16.h>
#include <stdint.h>

// ---------------------------------------------------------------------------
// SparseLinear: y[B,N] = x[B,M] @ W^T + bias, W given as CSR.
// R5: LDS-pipe relief. B fragments are 16 contiguous bytes/lane in global
// (B^T layout), so B skips LDS entirely: direct global_load_dwordx4 into a
// ping-pong register buffer, prefetched one K-step ahead (2x-unrolled loop,
// no reg copies). A stays in LDS with R2's measured-conflict-free pattern,
// double-buffered (16 KB total). LDS traffic per block-iter: 48 KB -> 24 KB.
// ---------------------------------------------------------------------------

#define B_DIM 4096
#define M_DIM 4096
#define N_DIM 4096
#define NNZ_ROW 819
#define BK 32

typedef __attribute__((ext_vector_type(8))) __bf16 bf16x8;
typedef __attribute__((ext_vector_type(4))) float f32x4;

__device__ __forceinline__ unsigned short f32_to_bf16(float f) {
    union { float f; unsigned int u; } v;
    v.f = f;
    unsigned int r = v.u + 0x7FFFu + ((v.u >> 16) & 1u);  // RNE
    return (unsigned short)(r >> 16);
}

__device__ __forceinline__ void load_lds16(const void* g, void* l) {
    __builtin_amdgcn_global_load_lds(
        (const __attribute__((address_space(1))) void*)g,
        (__attribute__((address_space(3))) void*)l,
        16, 0, 0);
}

// ---- prologue 1: densify one W row per block (verified R2) ----------------
__global__ __launch_bounds__(256) void densify_w(
    const float* __restrict__ wval,
    const int* __restrict__ cols,
    unsigned short* __restrict__ wb) {
    __shared__ __attribute__((aligned(16))) unsigned short row_s[M_DIM];  // 8 KB
    const int row = blockIdx.x;
    const int tid = threadIdx.x;
    uint4* rs4 = (uint4*)row_s;
    rs4[tid]       = make_uint4(0u, 0u, 0u, 0u);
    rs4[tid + 256] = make_uint4(0u, 0u, 0u, 0u);
    __syncthreads();
    const size_t base = (size_t)row * NNZ_ROW;
    for (int j = tid; j < NNZ_ROW; j += 256) {
        const int c = cols[base + j];
        row_s[c] = f32_to_bf16(wval[base + j]);
    }
    __syncthreads();
    uint4* dst = (uint4*)(wb + (size_t)row * M_DIM);
    dst[tid]       = rs4[tid];
    dst[tid + 256] = rs4[tid + 256];
}

// ---- prologue 2: X fp32 -> bf16 -------------------------------------------
__global__ __launch_bounds__(256) void cvt_x_bf16(
    const float4* __restrict__ x, uint4* __restrict__ y, int n8) {
    int i = blockIdx.x * 256 + threadIdx.x;
    if (i >= n8) return;
    const float4 a = x[2 * i];
    const float4 b = x[2 * i + 1];
    union { ushort ush[8]; uint4 u4; } o;
    o.ush[0] = f32_to_bf16(a.x); o.ush[1] = f32_to_bf16(a.y);
    o.ush[2] = f32_to_bf16(a.z); o.ush[3] = f32_to_bf16(a.w);
    o.ush[4] = f32_to_bf16(b.x); o.ush[5] = f32_to_bf16(b.y);
    o.ush[6] = f32_to_bf16(b.z); o.ush[7] = f32_to_bf16(b.w);
    y[i] = o.u4;
}

// ---- main GEMM: C[b,n] = sum_k Xb[b,k]*Wb[n,k] + bias[n] -------------------
// 128x128 block tile, BK=32, 4 waves 2x2, wave tile 64x64 = 4x4 of 16x16x32
// MFMA. A: LDS double-buffered (R2 conflict-free XOR pattern). B: direct
// global->register, ping-pong prefetch one K-step ahead.

__global__ __launch_bounds__(256, 3) void gemm_bt_bias(
    const unsigned short* __restrict__ Xb,   // [B][M] bf16 bits
    const unsigned short* __restrict__ Wb,   // [N][M] bf16 bits
    const float* __restrict__ bias,          // [N]
    float* __restrict__ out)                 // [B][N]
{
    __shared__ __attribute__((aligned(16))) unsigned short As[2 * 128 * BK]; // 16 KB

    const int tid    = threadIdx.x;
    const int wid    = tid >> 6;      // 0..3
    const int lane   = tid & 63;
    const int wm     = wid & 1;       // wave row (batch dim)
    const int wn     = wid >> 1;      // wave col (N dim)
    const int lane15 = lane & 15;
    const int laneq  = lane >> 4;     // 0..3

    const int bm0 = blockIdx.y * 128;
    const int bn0 = blockIdx.x * 128;

    // ---- A staging (R2 pattern): inst j covers rows j*16..j*16+15;
    // lane i -> row j*16+(i>>2), global k-chunk (i&3)^((i>>3)&3).
    const int srow = (lane >> 2);
    const int skof = ((lane & 3) ^ ((lane >> 3) & 3)) * 8;
    const unsigned short* aSrc0 =
        Xb + (size_t)(bm0 + wid * 16 + srow) * M_DIM + skof;
    const unsigned short* aSrc1 = aSrc0 + (size_t)64 * M_DIM;
    const int dOff0 = wid * 512;        // inst wid
    const int dOff1 = (wid + 4) * 512;  // inst wid+4

    // ---- A fragment read offsets (measured-conflict-free) ----
    const int slot = (laneq ^ ((lane15 >> 1) & 3)) * 8;
    int aOff[4];
#pragma unroll
    for (int t = 0; t < 4; ++t)
        aOff[t] = (wm * 64 + t * 16 + lane15) * BK + slot;

    // ---- B direct-from-global fragment pointers ----
    // frag t content: B[n = bn0+wn*64+t*16+lane15][kt + laneq*8 .. +7]
    // = 16 contiguous bytes; index with [kt>>3].
    const bf16x8* bP[4];
#pragma unroll
    for (int t = 0; t < 4; ++t) {
        const int nrow = bn0 + wn * 64 + t * 16 + lane15;
        bP[t] = (const bf16x8*)(Wb + (size_t)nrow * M_DIM + laneq * 8);
    }

    f32x4 acc[4][4];
#pragma unroll
    for (int i = 0; i < 4; ++i)
#pragma unroll
        for (int j = 0; j < 4; ++j) acc[i][j] = (f32x4)0.0f;

    // ---- prologue: stage A chunk 0 into buf0, load B chunk 0 ----
    load_lds16(aSrc0, As + dOff0);
    load_lds16(aSrc1, As + dOff1);
    bf16x8 b0[4], b1[4];
#pragma unroll
    for (int t = 0; t < 4; ++t) b0[t] = bP[t][0];
    __syncthreads();

    // 2x-unrolled ping-pong: 64 double-iterations
    for (int kt = 0; kt < M_DIM; kt += 2 * BK) {
        // -- half 1: compute (buf0, b0); prefetch kt+BK -> (buf1, b1) --
        load_lds16(aSrc0 + kt + BK, As + 128 * BK + dOff0);
        load_lds16(aSrc1 + kt + BK, As + 128 * BK + dOff1);
#pragma unroll
        for (int t = 0; t < 4; ++t) b1[t] = bP[t][(kt + BK) >> 3];
        {
            bf16x8 af[4];
#pragma unroll
            for (int t = 0; t < 4; ++t)
                af[t] = *((const bf16x8*)(As + aOff[t]));
#pragma unroll
            for (int mt = 0; mt < 4; ++mt)
#pragma unroll
                for (int nt = 0; nt < 4; ++nt)
                    acc[mt][nt] = __builtin_amdgcn_mfma_f32_16x16x32_bf16(
                        af[mt], b0[nt], acc[mt][nt], 0, 0, 0);
        }
        __syncthreads();

        // -- half 2: compute (buf1, b1); prefetch kt+2BK -> (buf0, b0) --
        if (kt + 2 * BK < M_DIM) {
            load_lds16(aSrc0 + kt + 2 * BK, As + dOff0);
            load_lds16(aSrc1 + kt + 2 * BK, As + dOff1);
#pragma unroll
            for (int t = 0; t < 4; ++t) b0[t] = bP[t][(kt + 2 * BK) >> 3];
        }
        {
            bf16x8 af[4];
#pragma unroll
            for (int t = 0; t < 4; ++t)
                af[t] = *((const bf16x8*)(As + 128 * BK + aOff[t]));
#pragma unroll
            for (int mt = 0; mt < 4; ++mt)
#pragma unroll
                for (int nt = 0; nt < 4; ++nt)
                    acc[mt][nt] = __builtin_amdgcn_mfma_f32_16x16x32_bf16(
                        af[mt], b1[nt], acc[mt][nt], 0, 0, 0);
        }
        __syncthreads();
    }

    // ---- epilogue: D elem r of acc[mt][nt] -> row = laneq*4+r, col = lane15
#pragma unroll
    for (int nt = 0; nt < 4; ++nt) {
        const int col = bn0 + wn * 64 + nt * 16 + lane15;
        const float bv = bias[col];
#pragma unroll
        for (int mt = 0; mt < 4; ++mt) {
            const int row0 = bm0 + wm * 64 + mt * 16 + laneq * 4;
#pragma unroll
            for (int r = 0; r < 4; ++r) {
                out[(size_t)(row0 + r) * N_DIM + col] = acc[mt][nt][r] + bv;
            }
        }
    }
}

// ---------------------------------------------------------------------------

extern "C" void kernel_launch(void* const* d_in, const int* in_sizes, int n_in,
                              void* d_out, int out_size, void* d_ws, size_t ws_size,
                              hipStream_t stream) {
    const float* x       = (const float*)d_in[0];
    const float* wval    = (const float*)d_in[1];
    const float* bias    = (const float*)d_in[2];
    const int*   cols    = (const int*)d_in[4];
    float* out = (float*)d_out;

    // workspace: Wb [N*M bf16] (32 MiB) | Xb [B*M bf16] (32 MiB)
    unsigned short* Wb = (unsigned short*)d_ws;
    unsigned short* Xb = Wb + (size_t)N_DIM * M_DIM;

    densify_w<<<dim3(N_DIM), dim3(256), 0, stream>>>(wval, cols, Wb);
    {
        int n8 = (B_DIM * M_DIM) / 8;
        cvt_x_bf16<<<dim3(n8 / 256), dim3(256), 0, stream>>>(
            (const float4*)x, (uint4*)Xb, n8);
    }
    gemm_bt_bias<<<dim3(N_DIM / 128, B_DIM / 128), dim3(256), 0, stream>>>(
        Xb, Wb, bias, out);
}